// Round 2
// baseline (1357.735 us; speedup 1.0000x reference)
//
#include <hip/hip_runtime.h>
#include <cstdint>
#include <cstddef>

typedef unsigned short u16;
typedef unsigned int u32;
typedef __attribute__((ext_vector_type(8))) short short8;
typedef __attribute__((ext_vector_type(4))) float floatx4;

#define NROWS 38400   // B*T = 64*600

// ---- workspace layout (bytes) ----
#define OFF_FLAG 0u
#define OFF_GI   64u           // [2][38400][120] f32 = 36,864,000
#define OFF_HCAT 36864064u     // [38400][80] f32    = 12,288,000
#define OFF_B1A  49152064u     // [256][576] bf16    =    294,912
#define OFF_B1B  49446976u     // [256][576] bf16    =    294,912
#define OFF_B2   49741888u     // [80][1472] bf16    =    235,520
#define OFF_B3   49977408u     // [272][1472] bf16   =    800,768  (end ~50.78 MB)
#define OFF_KO   OFF_GI        // kan1out [38400][80] f32 overlays dead GI

__device__ inline float bf2f(u16 u){ union{u32 i; float f;} v; v.i = ((u32)u)<<16; return v.f; }
__device__ inline u16 f2bf(float f){
  u32 u = __float_as_uint(f);
  return (u16)((u + 0x7FFFu + ((u>>16)&1u)) >> 16);   // RNE
}
// dtype-agnostic scalar load (isbf is wave-uniform)
__device__ inline float lodf(const void* p, size_t i, int isbf){
  return isbf ? bf2f(((const u16*)p)[i]) : ((const float*)p)[i];
}
__device__ inline float sigm(float x){ return 1.0f/(1.0f+__expf(-x)); }
__device__ inline float tanh_(float x){   // overflow-proof: e in (0,1]
  float e = __expf(-2.0f*fabsf(x)); float t = (1.0f-e)/(1.0f+e); return x<0.f ? -t : t;
}
__device__ inline float rdl(float v, int k){ return __int_as_float(__builtin_amdgcn_readlane(__float_as_int(v), k)); }

// ============================= detect input dtype (bf16 vs f32) =============================
__global__ void detect_kernel(const u16* __restrict__ xx, int* __restrict__ flag){
  const int l = threadIdx.x;                 // 64 lanes
  const u16 w = xx[2*l];                     // even u16s: bf16 values OR f32 low-mantissa halves
  const int e = (w>>7)&0xFF;
  const unsigned long long m = __ballot(e >= 100 && e <= 133);
  if (l == 0) *flag = (__popcll(m) >= 32) ? 1 : 0;   // 1 = bf16
}

// ============================= prep: build padded bf16 B^T matrices =============================
__global__ void prep_kernel(const void* __restrict__ f0Wih, const void* __restrict__ b0Wih,
                            const void* __restrict__ k1b, const void* __restrict__ k1s, const void* __restrict__ k1sc,
                            const void* __restrict__ k2b, const void* __restrict__ k2s, const void* __restrict__ k2sc,
                            const int* __restrict__ flag,
                            u16* __restrict__ B1a, u16* __restrict__ B1b,
                            u16* __restrict__ B2, u16* __restrict__ B3)
{
  const int isbf = *flag;
  const int idx = blockIdx.x*256 + threadIdx.x;
  if (idx < 73728){ // B1a/B1b: [256][576], logical (j<240, k<288), hi/lo split, A-pair duplication
    const int j = idx/288, k = idx - j*288;
    float w = 0.f;
    if (k < 257 && j < 240)
      w = (j < 120) ? lodf(f0Wih, (size_t)j*257+k, isbf) : lodf(b0Wih, (size_t)(j-120)*257+k, isbf);
    const u16 hi = f2bf(w); const u16 lo = f2bf(w - bf2f(hi));
    B1a[(size_t)j*576 + 2*k] = hi; B1a[(size_t)j*576 + 2*k+1] = hi;
    B1b[(size_t)j*576 + 2*k] = lo; B1b[(size_t)j*576 + 2*k+1] = 0;
  } else if (idx < 132608){ // B2: [80][736 logical m], duplicated into k=2m,2m+1
    const int t = idx - 73728; const int n = t/736, m = t - n*736;
    float v = 0.f;
    if (m < 80) v = lodf(k1b, (size_t)n*80+m, isbf);
    else if (m >= 96){ const int m2 = m-96, i = m2>>3, g = m2&7;
      v = lodf(k1s, ((size_t)n*80+i)*8+g, isbf) * lodf(k1sc, (size_t)n*80+i, isbf); }
    const u16 vv = f2bf(v);
    B2[(size_t)n*1472 + 2*m] = vv; B2[(size_t)n*1472 + 2*m+1] = vv;
  } else { // B3: [272][736 logical m]; rows >=257 zero
    const int t = idx - 132608; const int n = t/736, m = t - n*736;
    float v = 0.f;
    if (n < 257){
      if (m < 80) v = lodf(k2b, (size_t)n*80+m, isbf);
      else if (m >= 96){ const int m2 = m-96, i = m2>>3, g = m2&7;
        v = lodf(k2s, ((size_t)n*80+i)*8+g, isbf) * lodf(k2sc, (size_t)n*80+i, isbf); }
    }
    const u16 vv = f2bf(v);
    B3[(size_t)n*1472 + 2*m] = vv; B3[(size_t)n*1472 + 2*m+1] = vv;
  }
}

// ============================= G1: gi = x @ Wih^T + bih (both dirs), hi/lo MFMA =============================
__launch_bounds__(256)
__global__ void g1_kernel(const void* __restrict__ x, const u16* __restrict__ B1a, const u16* __restrict__ B1b,
                          const void* __restrict__ f0bih, const void* __restrict__ b0bih,
                          const int* __restrict__ flag, float* __restrict__ gi)
{
  __shared__ __attribute__((aligned(16))) u16 As[32][576];   // hi/lo interleaved, K 257->288 logical
  const int isbf = *flag;
  const int tid = threadIdx.x;
  const size_t r0 = (size_t)blockIdx.x * 32;
  {
    const int row = tid>>3, kk = tid&7;
    #pragma unroll
    for (int it=0; it<36; ++it){
      const int k = kk + it*8;
      const float v = (k < 257) ? lodf(x, (r0+row)*257 + k, isbf) : 0.f;
      const u16 hi = f2bf(v);
      As[row][2*k] = hi; As[row][2*k+1] = f2bf(v - bf2f(hi));
    }
  }
  __syncthreads();
  const int w = tid>>6, l = tid&63, m16 = l&15, q4 = l>>4;
  const int slab = w>>1, ch = w&1;
  floatx4 acc[8];
  #pragma unroll
  for (int j=0;j<8;++j){ floatx4 z={0.f,0.f,0.f,0.f}; acc[j]=z; }
  #pragma unroll 1
  for (int ks=0; ks<18; ++ks){
    const short8 a = *(const short8*)&As[slab*16+m16][ks*32 + q4*8];
    #pragma unroll
    for (int j=0;j<8;++j){
      const int nt = ch*8+j;
      const short8 ba = *(const short8*)&B1a[(size_t)(nt*16+m16)*576 + ks*32 + q4*8];
      acc[j] = __builtin_amdgcn_mfma_f32_16x16x32_bf16(a, ba, acc[j], 0, 0, 0);
      const short8 bb = *(const short8*)&B1b[(size_t)(nt*16+m16)*576 + ks*32 + q4*8];
      acc[j] = __builtin_amdgcn_mfma_f32_16x16x32_bf16(a, bb, acc[j], 0, 0, 0);
    }
  }
  #pragma unroll
  for (int j=0;j<8;++j){
    const int col = (ch*8+j)*16 + m16;
    if (col < 240){
      const int dsel = (col < 120) ? 0 : 1;
      const int jj = (col < 120) ? col : col-120;
      const float bias = (col < 120) ? lodf(f0bih, col, isbf) : lodf(b0bih, col-120, isbf);
      #pragma unroll
      for (int rg=0; rg<4; ++rg){
        const size_t row = r0 + slab*16 + q4*4 + rg;
        gi[((size_t)dsel*NROWS + row)*120 + jj] = acc[j][rg] + bias;
      }
    }
  }
}

// ============================= GRU: 2-layer pipelined recurrence, 1 block per (dir,batch) =============================
__device__ inline void stage_chunk(const char* __restrict__ gid, int4* dst, int c, int d, int bat, int l)
{
  const long long rbase = (long long)bat*600 + (d ? (536 - 64*c) : (64*c));
  const long long base = rbase * 480;
  const long long lim = (long long)NROWS * 480;
  #pragma unroll
  for (int bt=0; bt<5; ++bt){
    int4 v[6];
    #pragma unroll
    for (int j=0; j<6; ++j){
      const long long off = base + (long long)((bt*6+j)*64 + l)*16;
      int4 z; z.x=0; z.y=0; z.z=0; z.w=0;
      v[j] = (off >= 0 && off+16 <= lim) ? *(const int4*)(gid + off) : z;
    }
    #pragma unroll
    for (int j=0; j<6; ++j) dst[(bt*6+j)*64 + l] = v[j];
  }
}

__launch_bounds__(256)
__global__ void gru_kernel(const float* __restrict__ gi,
  const void* __restrict__ f0Whh, const void* __restrict__ f0bhh,
  const void* __restrict__ f1Wih, const void* __restrict__ f1Whh, const void* __restrict__ f1bih, const void* __restrict__ f1bhh,
  const void* __restrict__ b0Whh, const void* __restrict__ b0bhh,
  const void* __restrict__ b1Wih, const void* __restrict__ b1Whh, const void* __restrict__ b1bih, const void* __restrict__ b1bhh,
  const int* __restrict__ flag, float* __restrict__ hcat)
{
  __shared__ int4 chunkbuf[2][1920];
  __shared__ float h0buf[2][40];
  __shared__ float gi1buf[2][3][40];
  const int isbf = *flag;
  const int tid = threadIdx.x, w = tid>>6, l = tid&63;
  const int blk = blockIdx.x, d = blk>>6, bat = blk&63;
  const int li = (l < 40) ? l : 39;
  const char* gid = (const char*)(gi + (size_t)d*NROWS*120);

  const void *Wsrc = 0, *bsrc = 0;
  if (w == 0){ Wsrc = d ? b0Whh : f0Whh; bsrc = d ? b0bhh : f0bhh; }
  else if (w == 1){ Wsrc = d ? b1Wih : f1Wih; bsrc = d ? b1bih : f1bih; }
  else if (w == 2){ Wsrc = d ? b1Whh : f1Whh; bsrc = d ? b1bhh : f1bhh; }

  float WA[40], WB[40], WC[40];
  float bA = 0.f, bB = 0.f, bC = 0.f;
  if (w < 3){
    #pragma unroll
    for (int k=0; k<40; ++k){
      WA[k] = lodf(Wsrc, (size_t)(     li)*40 + k, isbf);
      WB[k] = lodf(Wsrc, (size_t)(40 + li)*40 + k, isbf);
      WC[k] = lodf(Wsrc, (size_t)(80 + li)*40 + k, isbf);
    }
    bA = lodf(bsrc, li, isbf); bB = lodf(bsrc, 40+li, isbf); bC = lodf(bsrc, 80+li, isbf);
  } else {
    stage_chunk(gid, &chunkbuf[0][0], 0, d, bat, l);
  }
  float hstate = 0.f;
  __syncthreads();

  #pragma unroll 1
  for (int u=0; u<602; ++u){
    if (w == 0){
      if (u < 600){
        const int t = u, cc = t>>6, tin = t&63;
        const int rowin = d ? (63 - tin) : tin;
        const float* girow = (const float*)((const char*)&chunkbuf[cc&1][0] + rowin*480);
        const float gA = girow[li], gB = girow[40+li], gC = girow[80+li];
        float ar = bA, az = bB, an = bC;
        #pragma unroll
        for (int k=0; k<40; ++k){ const float hk = rdl(hstate, k); ar += WA[k]*hk; az += WB[k]*hk; an += WC[k]*hk; }
        const float r = sigm(gA + ar), z = sigm(gB + az);
        const float n = tanh_(gC + r*an);
        hstate = (1.f - z)*n + z*hstate;
        if (l < 40) h0buf[u&1][l] = hstate;
      }
    } else if (w == 1){
      if (u >= 1 && u < 601){
        const float h0p = h0buf[(u-1)&1][li];
        float ar = bA, az = bB, an = bC;
        #pragma unroll
        for (int k=0; k<40; ++k){ const float hk = rdl(h0p, k); ar += WA[k]*hk; az += WB[k]*hk; an += WC[k]*hk; }
        if (l < 40){ gi1buf[u&1][0][l] = ar; gi1buf[u&1][1][l] = az; gi1buf[u&1][2][l] = an; }
      }
    } else if (w == 2){
      if (u >= 2){
        const float gA = gi1buf[(u-1)&1][0][li], gB = gi1buf[(u-1)&1][1][li], gC = gi1buf[(u-1)&1][2][li];
        float ar = bA, az = bB, an = bC;
        #pragma unroll
        for (int k=0; k<40; ++k){ const float hk = rdl(hstate, k); ar += WA[k]*hk; az += WB[k]*hk; an += WC[k]*hk; }
        const float r = sigm(gA + ar), z = sigm(gB + az);
        const float n = tanh_(gC + r*an);
        hstate = (1.f - z)*n + z*hstate;
        if (l < 40) hcat[((size_t)bat*600 + (u-2))*80 + d*40 + l] = hstate;
      }
    } else {
      if ((u & 63) == 0){ const int c1 = (u>>6) + 1; if (c1 <= 9) stage_chunk(gid, &chunkbuf[c1&1][0], c1, d, bat, l); }
    }
    __syncthreads();
  }
}

// ============================= KAN: fused A-construction (hi/lo bf16) + MFMA GEMM =============================
__device__ inline void spline8(float x, float* bs)
{
  float g[12];
  #pragma unroll
  for (int j=0; j<12; ++j) g[j] = (float)(j-3)*0.4f - 1.0f;
  float b0[11];
  #pragma unroll
  for (int j=0; j<11; ++j) b0[j] = (x >= g[j] && x < g[j+1]) ? 1.f : 0.f;
  float b1[10];
  #pragma unroll
  for (int j=0; j<10; ++j)
    b1[j] = (x - g[j])*(1.0f/(g[j+1]-g[j]))*b0[j] + (g[j+2] - x)*(1.0f/(g[j+2]-g[j+1]))*b0[j+1];
  float b2[9];
  #pragma unroll
  for (int j=0; j<9; ++j)
    b2[j] = (x - g[j])*(1.0f/(g[j+2]-g[j]))*b1[j] + (g[j+3] - x)*(1.0f/(g[j+3]-g[j+1]))*b1[j+1];
  #pragma unroll
  for (int j=0; j<8; ++j)
    bs[j] = (x - g[j])*(1.0f/(g[j+3]-g[j]))*b2[j] + (g[j+4] - x)*(1.0f/(g[j+4]-g[j+1]))*b2[j+1];
}

template<int NT, bool FINAL>
__launch_bounds__(256)
__global__ void kan_kernel(const float* __restrict__ Xin, const u16* __restrict__ Bmat,
                           float* __restrict__ Yout, void* __restrict__ Obuf,
                           const void* __restrict__ slope, const int* __restrict__ flag)
{
  __shared__ __attribute__((aligned(16))) float xs[64][80];
  __shared__ __attribute__((aligned(16))) u16 abase[64][192];
  __shared__ __attribute__((aligned(16))) u16 asp[64][128];
  const int isbf = *flag;
  const int tid = threadIdx.x;
  const size_t r0 = (size_t)blockIdx.x * 64;

  for (int idx=tid; idx<5120; idx+=256) ((float*)xs)[idx] = Xin[r0*80 + idx];
  __syncthreads();
  for (int idx=tid; idx<6144; idx+=256){
    const int row = idx/96, m = idx - row*96;
    float v = 0.f;
    if (m < 80){ const float xv = xs[row][m]; v = xv * sigm(xv); }
    const u16 hi = f2bf(v);
    abase[row][2*m] = hi; abase[row][2*m+1] = f2bf(v - bf2f(hi));
  }
  __syncthreads();

  const int w = tid>>6, l = tid&63, m16 = l&15, q4 = l>>4;
  const int arow = w*16 + m16;
  floatx4 acc[NT];
  #pragma unroll
  for (int nt=0; nt<NT; ++nt){ floatx4 z = {0.f,0.f,0.f,0.f}; acc[nt] = z; }

  #pragma unroll 1
  for (int ks=0; ks<6; ++ks){
    const short8 a = *(const short8*)&abase[arow][ks*32 + q4*8];
    #pragma unroll
    for (int nt=0; nt<NT; ++nt){
      const short8 bb = *(const short8*)&Bmat[(size_t)(nt*16+m16)*1472 + ks*32 + q4*8];
      acc[nt] = __builtin_amdgcn_mfma_f32_16x16x32_bf16(a, bb, acc[nt], 0, 0, 0);
    }
  }
  #pragma unroll 1
  for (int c=0; c<10; ++c){
    __syncthreads();
    for (int idx=tid; idx<512; idx+=256){
      const int row = idx>>3, il = idx&7;
      const float xv = xs[row][c*8 + il];
      float bs[8]; spline8(xv, bs);
      union { u16 us[16]; short8 v2[2]; } pk;
      #pragma unroll
      for (int j=0; j<8; ++j){ const u16 hi = f2bf(bs[j]); pk.us[2*j] = hi; pk.us[2*j+1] = f2bf(bs[j] - bf2f(hi)); }
      *(short8*)&asp[row][il*16]     = pk.v2[0];
      *(short8*)&asp[row][il*16 + 8] = pk.v2[1];
    }
    __syncthreads();
    #pragma unroll 1
    for (int ks=0; ks<4; ++ks){
      const short8 a = *(const short8*)&asp[arow][ks*32 + q4*8];
      const int kg = 192 + c*128 + ks*32 + q4*8;
      #pragma unroll
      for (int nt=0; nt<NT; ++nt){
        const short8 bb = *(const short8*)&Bmat[(size_t)(nt*16+m16)*1472 + kg];
        acc[nt] = __builtin_amdgcn_mfma_f32_16x16x32_bf16(a, bb, acc[nt], 0, 0, 0);
      }
    }
  }

  #pragma unroll
  for (int nt=0; nt<NT; ++nt){
    const int col = nt*16 + m16;
    #pragma unroll
    for (int rg=0; rg<4; ++rg){
      const size_t row = r0 + w*16 + q4*4 + rg;
      const float v = acc[nt][rg];
      if constexpr (!FINAL){
        Yout[row*80 + col] = v;
      } else {
        if (col < 257){
          const float s = lodf(slope, col, isbf);
          const float o = 1.2f * sigm(s*v);
          if (isbf) ((u16*)Obuf)[row*257 + col] = f2bf(o);
          else      ((float*)Obuf)[row*257 + col] = o;
        }
      }
    }
  }
}

// ============================= launcher =============================
extern "C" void kernel_launch(void* const* d_in, const int* in_sizes, int n_in,
                              void* d_out, int out_size, void* d_ws, size_t ws_size,
                              hipStream_t stream)
{
  (void)in_sizes; (void)n_in; (void)out_size; (void)ws_size;
  const void* x     = d_in[0];
  // d_in[1] = lengths (unused)
  const void* f0Wih = d_in[2];  const void* f0Whh = d_in[3];
  const void* f0bih = d_in[4];  const void* f0bhh = d_in[5];
  const void* f1Wih = d_in[6];  const void* f1Whh = d_in[7];
  const void* f1bih = d_in[8];  const void* f1bhh = d_in[9];
  const void* b0Wih = d_in[10]; const void* b0Whh = d_in[11];
  const void* b0bih = d_in[12]; const void* b0bhh = d_in[13];
  const void* b1Wih = d_in[14]; const void* b1Whh = d_in[15];
  const void* b1bih = d_in[16]; const void* b1bhh = d_in[17];
  const void* k1b   = d_in[18]; const void* k1s   = d_in[19]; const void* k1sc = d_in[20];
  const void* k2b   = d_in[21]; const void* k2s   = d_in[22]; const void* k2sc = d_in[23];
  const void* slope = d_in[24];

  char* ws = (char*)d_ws;
  int*   flag  = (int*)(ws + OFF_FLAG);
  float* gi    = (float*)(ws + OFF_GI);
  float* hcat  = (float*)(ws + OFF_HCAT);
  float* k1out = (float*)(ws + OFF_KO);
  u16* B1a = (u16*)(ws + OFF_B1A);
  u16* B1b = (u16*)(ws + OFF_B1B);
  u16* B2  = (u16*)(ws + OFF_B2);
  u16* B3  = (u16*)(ws + OFF_B3);

  detect_kernel<<<1, 64, 0, stream>>>((const u16*)x, flag);
  prep_kernel<<<1300, 256, 0, stream>>>(f0Wih, b0Wih, k1b, k1s, k1sc, k2b, k2s, k2sc, flag, B1a, B1b, B2, B3);
  g1_kernel<<<1200, 256, 0, stream>>>(x, B1a, B1b, f0bih, b0bih, flag, gi);
  gru_kernel<<<128, 256, 0, stream>>>(gi,
      f0Whh, f0bhh, f1Wih, f1Whh, f1bih, f1bhh,
      b0Whh, b0bhh, b1Wih, b1Whh, b1bih, b1bhh, flag, hcat);
  kan_kernel<5,  false><<<600, 256, 0, stream>>>(hcat, B2, k1out, nullptr, nullptr, flag);
  kan_kernel<17, true ><<<600, 256, 0, stream>>>(k1out, B3, nullptr, d_out, slope, flag);
}

// Round 3
// 1335.286 us; speedup vs baseline: 1.0168x; 1.0168x over previous
//
#include <hip/hip_runtime.h>
#include <cstdint>
#include <cstddef>

typedef unsigned short u16;
typedef unsigned int u32;
typedef __attribute__((ext_vector_type(8))) short short8;
typedef __attribute__((ext_vector_type(4))) float floatx4;

#define NROWS 38400   // B*T = 64*600

// ---- workspace layout (bytes) ----
#define OFF_FLAG 0u
#define OFF_GI   64u           // [2][38400][120] f32 = 36,864,000
#define OFF_HCAT 36864064u     // [38400][80] f32    = 12,288,000
#define OFF_B1A  49152064u     // [256][576] bf16    =    294,912
#define OFF_B1B  49446976u     // [256][576] bf16    =    294,912
#define OFF_B2   49741888u     // [80][1472] bf16    =    235,520
#define OFF_B3   49977408u     // [272][1472] bf16   =    800,768  (end ~50.78 MB)
#define OFF_KO   OFF_GI        // kan1out [38400][80] f32 overlays dead GI

__device__ inline float bf2f(u16 u){ union{u32 i; float f;} v; v.i = ((u32)u)<<16; return v.f; }
__device__ inline u16 f2bf(float f){
  u32 u = __float_as_uint(f);
  return (u16)((u + 0x7FFFu + ((u>>16)&1u)) >> 16);   // RNE
}
// dtype-agnostic scalar load (isbf is wave-uniform)
__device__ inline float lodf(const void* p, size_t i, int isbf){
  return isbf ? bf2f(((const u16*)p)[i]) : ((const float*)p)[i];
}
__device__ inline float rcpf(float x){ return __builtin_amdgcn_rcpf(x); }
__device__ inline float sigm(float x){ return rcpf(1.0f+__expf(-x)); }
__device__ inline float tanh_(float x){   // overflow-proof: e in (0,1]
  float e = __expf(-2.0f*fabsf(x)); float t = (1.0f-e)*rcpf(1.0f+e); return x<0.f ? -t : t;
}
__device__ inline float rdl(float v, int k){ return __int_as_float(__builtin_amdgcn_readlane(__float_as_int(v), k)); }

// ============================= detect input dtype (bf16 vs f32) =============================
__global__ void detect_kernel(const u16* __restrict__ xx, int* __restrict__ flag){
  const int l = threadIdx.x;                 // 64 lanes
  const u16 w = xx[2*l];                     // even u16s: bf16 values OR f32 low-mantissa halves
  const int e = (w>>7)&0xFF;
  const unsigned long long m = __ballot(e >= 100 && e <= 133);
  if (l == 0) *flag = (__popcll(m) >= 32) ? 1 : 0;   // 1 = bf16
}

// ============================= prep: build padded bf16 B^T matrices =============================
__global__ void prep_kernel(const void* __restrict__ f0Wih, const void* __restrict__ b0Wih,
                            const void* __restrict__ k1b, const void* __restrict__ k1s, const void* __restrict__ k1sc,
                            const void* __restrict__ k2b, const void* __restrict__ k2s, const void* __restrict__ k2sc,
                            const int* __restrict__ flag,
                            u16* __restrict__ B1a, u16* __restrict__ B1b,
                            u16* __restrict__ B2, u16* __restrict__ B3)
{
  const int isbf = *flag;
  const int idx = blockIdx.x*256 + threadIdx.x;
  if (idx < 73728){ // B1a/B1b: [256][576], logical (j<240, k<288), hi/lo split, A-pair duplication
    const int j = idx/288, k = idx - j*288;
    float w = 0.f;
    if (k < 257 && j < 240)
      w = (j < 120) ? lodf(f0Wih, (size_t)j*257+k, isbf) : lodf(b0Wih, (size_t)(j-120)*257+k, isbf);
    const u16 hi = f2bf(w); const u16 lo = f2bf(w - bf2f(hi));
    B1a[(size_t)j*576 + 2*k] = hi; B1a[(size_t)j*576 + 2*k+1] = hi;
    B1b[(size_t)j*576 + 2*k] = lo; B1b[(size_t)j*576 + 2*k+1] = 0;
  } else if (idx < 132608){ // B2: [80][736 logical m], duplicated into k=2m,2m+1
    const int t = idx - 73728; const int n = t/736, m = t - n*736;
    float v = 0.f;
    if (m < 80) v = lodf(k1b, (size_t)n*80+m, isbf);
    else if (m >= 96){ const int m2 = m-96, i = m2>>3, g = m2&7;
      v = lodf(k1s, ((size_t)n*80+i)*8+g, isbf) * lodf(k1sc, (size_t)n*80+i, isbf); }
    const u16 vv = f2bf(v);
    B2[(size_t)n*1472 + 2*m] = vv; B2[(size_t)n*1472 + 2*m+1] = vv;
  } else { // B3: [272][736 logical m]; rows >=257 zero
    const int t = idx - 132608; const int n = t/736, m = t - n*736;
    float v = 0.f;
    if (n < 257){
      if (m < 80) v = lodf(k2b, (size_t)n*80+m, isbf);
      else if (m >= 96){ const int m2 = m-96, i = m2>>3, g = m2&7;
        v = lodf(k2s, ((size_t)n*80+i)*8+g, isbf) * lodf(k2sc, (size_t)n*80+i, isbf); }
    }
    const u16 vv = f2bf(v);
    B3[(size_t)n*1472 + 2*m] = vv; B3[(size_t)n*1472 + 2*m+1] = vv;
  }
}

// ============================= G1: gi = x @ Wih^T + bih (both dirs), hi/lo MFMA =============================
__launch_bounds__(256)
__global__ void g1_kernel(const void* __restrict__ x, const u16* __restrict__ B1a, const u16* __restrict__ B1b,
                          const void* __restrict__ f0bih, const void* __restrict__ b0bih,
                          const int* __restrict__ flag, float* __restrict__ gi)
{
  __shared__ __attribute__((aligned(16))) u16 As[32][576];   // hi/lo interleaved, K 257->288 logical
  const int isbf = *flag;
  const int tid = threadIdx.x;
  const size_t r0 = (size_t)blockIdx.x * 32;
  {
    const int row = tid>>3, kk = tid&7;
    #pragma unroll
    for (int it=0; it<36; ++it){
      const int k = kk + it*8;
      const float v = (k < 257) ? lodf(x, (r0+row)*257 + k, isbf) : 0.f;
      const u16 hi = f2bf(v);
      As[row][2*k] = hi; As[row][2*k+1] = f2bf(v - bf2f(hi));
    }
  }
  __syncthreads();
  const int w = tid>>6, l = tid&63, m16 = l&15, q4 = l>>4;
  const int slab = w>>1, ch = w&1;
  floatx4 acc[8];
  #pragma unroll
  for (int j=0;j<8;++j){ floatx4 z={0.f,0.f,0.f,0.f}; acc[j]=z; }
  if (isbf){ // bf16 inputs: lo limbs of B are exactly zero -> single pass
    #pragma unroll 1
    for (int ks=0; ks<18; ++ks){
      const short8 a = *(const short8*)&As[slab*16+m16][ks*32 + q4*8];
      #pragma unroll
      for (int j=0;j<8;++j){
        const int nt = ch*8+j;
        const short8 ba = *(const short8*)&B1a[(size_t)(nt*16+m16)*576 + ks*32 + q4*8];
        acc[j] = __builtin_amdgcn_mfma_f32_16x16x32_bf16(a, ba, acc[j], 0, 0, 0);
      }
    }
  } else {
    #pragma unroll 1
    for (int ks=0; ks<18; ++ks){
      const short8 a = *(const short8*)&As[slab*16+m16][ks*32 + q4*8];
      #pragma unroll
      for (int j=0;j<8;++j){
        const int nt = ch*8+j;
        const short8 ba = *(const short8*)&B1a[(size_t)(nt*16+m16)*576 + ks*32 + q4*8];
        acc[j] = __builtin_amdgcn_mfma_f32_16x16x32_bf16(a, ba, acc[j], 0, 0, 0);
        const short8 bb = *(const short8*)&B1b[(size_t)(nt*16+m16)*576 + ks*32 + q4*8];
        acc[j] = __builtin_amdgcn_mfma_f32_16x16x32_bf16(a, bb, acc[j], 0, 0, 0);
      }
    }
  }
  #pragma unroll
  for (int j=0;j<8;++j){
    const int col = (ch*8+j)*16 + m16;
    if (col < 240){
      const int dsel = (col < 120) ? 0 : 1;
      const int jj = (col < 120) ? col : col-120;
      const float bias = (col < 120) ? lodf(f0bih, col, isbf) : lodf(b0bih, col-120, isbf);
      #pragma unroll
      for (int rg=0; rg<4; ++rg){
        const size_t row = r0 + slab*16 + q4*4 + rg;
        gi[((size_t)dsel*NROWS + row)*120 + jj] = acc[j][rg] + bias;
      }
    }
  }
}

// ============================= GRU: 2-layer pipelined recurrence, 1 block per (dir,batch) =============================
__device__ inline void stage_chunk(const char* __restrict__ gid, int4* dst, int c, int d, int bat, int l)
{
  const long long rbase = (long long)bat*600 + (d ? (536 - 64*c) : (64*c));
  const long long base = rbase * 480;
  const long long lim = (long long)NROWS * 480;
  #pragma unroll
  for (int bt=0; bt<5; ++bt){
    int4 v[6];
    #pragma unroll
    for (int j=0; j<6; ++j){
      const long long off = base + (long long)((bt*6+j)*64 + l)*16;
      int4 z; z.x=0; z.y=0; z.z=0; z.w=0;
      v[j] = (off >= 0 && off+16 <= lim) ? *(const int4*)(gid + off) : z;
    }
    #pragma unroll
    for (int j=0; j<6; ++j) dst[(bt*6+j)*64 + l] = v[j];
  }
}

__launch_bounds__(256, 1)   // 1 wave/EU min -> up to 256 VGPRs: keep 120-float weight arrays register-resident
__global__ void gru_kernel(const float* __restrict__ gi,
  const void* __restrict__ f0Whh, const void* __restrict__ f0bhh,
  const void* __restrict__ f1Wih, const void* __restrict__ f1Whh, const void* __restrict__ f1bih, const void* __restrict__ f1bhh,
  const void* __restrict__ b0Whh, const void* __restrict__ b0bhh,
  const void* __restrict__ b1Wih, const void* __restrict__ b1Whh, const void* __restrict__ b1bih, const void* __restrict__ b1bhh,
  const int* __restrict__ flag, float* __restrict__ hcat)
{
  __shared__ int4 chunkbuf[2][1920];
  __shared__ float h0buf[2][40];
  __shared__ float gi1buf[2][3][40];
  const int isbf = *flag;
  const int tid = threadIdx.x, w = tid>>6, l = tid&63;
  const int blk = blockIdx.x, d = blk>>6, bat = blk&63;
  const int li = (l < 40) ? l : 39;
  const char* gid = (const char*)(gi + (size_t)d*NROWS*120);

  const void *Wsrc = 0, *bsrc = 0;
  if (w == 0){ Wsrc = d ? b0Whh : f0Whh; bsrc = d ? b0bhh : f0bhh; }
  else if (w == 1){ Wsrc = d ? b1Wih : f1Wih; bsrc = d ? b1bih : f1bih; }
  else if (w == 2){ Wsrc = d ? b1Whh : f1Whh; bsrc = d ? b1bhh : f1bhh; }

  float WA[40], WB[40], WC[40];
  float bA = 0.f, bB = 0.f, bC = 0.f;
  if (w < 3){
    #pragma unroll
    for (int k=0; k<40; ++k){
      WA[k] = lodf(Wsrc, (size_t)(     li)*40 + k, isbf);
      WB[k] = lodf(Wsrc, (size_t)(40 + li)*40 + k, isbf);
      WC[k] = lodf(Wsrc, (size_t)(80 + li)*40 + k, isbf);
    }
    bA = lodf(bsrc, li, isbf); bB = lodf(bsrc, 40+li, isbf); bC = lodf(bsrc, 80+li, isbf);
  } else {
    stage_chunk(gid, &chunkbuf[0][0], 0, d, bat, l);
  }
  float hstate = 0.f;
  __syncthreads();

  #pragma unroll 1
  for (int u=0; u<602; ++u){
    if (w == 0){
      if (u < 600){
        const int t = u, cc = t>>6, tin = t&63;
        const int rowin = d ? (63 - tin) : tin;
        const float* girow = (const float*)((const char*)&chunkbuf[cc&1][0] + rowin*480);
        const float gA = girow[li], gB = girow[40+li], gC = girow[80+li];
        float ar = bA, az = bB, an = bC;
        #pragma unroll
        for (int k=0; k<40; ++k){ const float hk = rdl(hstate, k); ar += WA[k]*hk; az += WB[k]*hk; an += WC[k]*hk; }
        const float r = sigm(gA + ar), z = sigm(gB + az);
        const float n = tanh_(gC + r*an);
        hstate = (1.f - z)*n + z*hstate;
        if (l < 40) h0buf[u&1][l] = hstate;
      }
    } else if (w == 1){
      if (u >= 1 && u < 601){
        const float h0p = h0buf[(u-1)&1][li];
        float ar = bA, az = bB, an = bC;
        #pragma unroll
        for (int k=0; k<40; ++k){ const float hk = rdl(h0p, k); ar += WA[k]*hk; az += WB[k]*hk; an += WC[k]*hk; }
        if (l < 40){ gi1buf[u&1][0][l] = ar; gi1buf[u&1][1][l] = az; gi1buf[u&1][2][l] = an; }
      }
    } else if (w == 2){
      if (u >= 2){
        const float gA = gi1buf[(u-1)&1][0][li], gB = gi1buf[(u-1)&1][1][li], gC = gi1buf[(u-1)&1][2][li];
        float ar = bA, az = bB, an = bC;
        #pragma unroll
        for (int k=0; k<40; ++k){ const float hk = rdl(hstate, k); ar += WA[k]*hk; az += WB[k]*hk; an += WC[k]*hk; }
        const float r = sigm(gA + ar), z = sigm(gB + az);
        const float n = tanh_(gC + r*an);
        hstate = (1.f - z)*n + z*hstate;
        if (l < 40) hcat[((size_t)bat*600 + (u-2))*80 + d*40 + l] = hstate;
      }
    } else {
      if ((u & 63) == 0){ const int c1 = (u>>6) + 1; if (c1 <= 9) stage_chunk(gid, &chunkbuf[c1&1][0], c1, d, bat, l); }
    }
    __syncthreads();
  }
}

// ============================= KAN: fused A-construction (hi/lo bf16) + MFMA GEMM =============================
__device__ inline void spline8(float x, float* bs)
{
  float g[12];
  #pragma unroll
  for (int j=0; j<12; ++j) g[j] = (float)(j-3)*0.4f - 1.0f;
  float b0[11];
  #pragma unroll
  for (int j=0; j<11; ++j) b0[j] = (x >= g[j] && x < g[j+1]) ? 1.f : 0.f;
  float b1[10];
  #pragma unroll
  for (int j=0; j<10; ++j)
    b1[j] = (x - g[j])*(1.0f/(g[j+1]-g[j]))*b0[j] + (g[j+2] - x)*(1.0f/(g[j+2]-g[j+1]))*b0[j+1];
  float b2[9];
  #pragma unroll
  for (int j=0; j<9; ++j)
    b2[j] = (x - g[j])*(1.0f/(g[j+2]-g[j]))*b1[j] + (g[j+3] - x)*(1.0f/(g[j+3]-g[j+1]))*b1[j+1];
  #pragma unroll
  for (int j=0; j<8; ++j)
    bs[j] = (x - g[j])*(1.0f/(g[j+3]-g[j]))*b2[j] + (g[j+4] - x)*(1.0f/(g[j+4]-g[j+1]))*b2[j+1];
}

template<int NT, bool FINAL>
__launch_bounds__(256)
__global__ void kan_kernel(const float* __restrict__ Xin, const u16* __restrict__ Bmat,
                           float* __restrict__ Yout, void* __restrict__ Obuf,
                           const void* __restrict__ slope, const int* __restrict__ flag)
{
  __shared__ __attribute__((aligned(16))) float xs[64][80];
  __shared__ __attribute__((aligned(16))) u16 abase[64][192];
  __shared__ __attribute__((aligned(16))) u16 asp[64][128];
  const int isbf = *flag;
  const int tid = threadIdx.x;
  const size_t r0 = (size_t)blockIdx.x * 64;

  for (int idx=tid; idx<5120; idx+=256) ((float*)xs)[idx] = Xin[r0*80 + idx];
  __syncthreads();
  for (int idx=tid; idx<6144; idx+=256){
    const int row = idx/96, m = idx - row*96;
    float v = 0.f;
    if (m < 80){ const float xv = xs[row][m]; v = xv * sigm(xv); }
    const u16 hi = f2bf(v);
    abase[row][2*m] = hi; abase[row][2*m+1] = f2bf(v - bf2f(hi));
  }
  __syncthreads();

  const int w = tid>>6, l = tid&63, m16 = l&15, q4 = l>>4;
  const int arow = w*16 + m16;
  floatx4 acc[NT];
  #pragma unroll
  for (int nt=0; nt<NT; ++nt){ floatx4 z = {0.f,0.f,0.f,0.f}; acc[nt] = z; }

  #pragma unroll 1
  for (int ks=0; ks<6; ++ks){
    const short8 a = *(const short8*)&abase[arow][ks*32 + q4*8];
    #pragma unroll
    for (int nt=0; nt<NT; ++nt){
      const short8 bb = *(const short8*)&Bmat[(size_t)(nt*16+m16)*1472 + ks*32 + q4*8];
      acc[nt] = __builtin_amdgcn_mfma_f32_16x16x32_bf16(a, bb, acc[nt], 0, 0, 0);
    }
  }
  #pragma unroll 1
  for (int c=0; c<10; ++c){
    __syncthreads();
    for (int idx=tid; idx<512; idx+=256){
      const int row = idx>>3, il = idx&7;
      const float xv = xs[row][c*8 + il];
      float bs[8]; spline8(xv, bs);
      union { u16 us[16]; short8 v2[2]; } pk;
      #pragma unroll
      for (int j=0; j<8; ++j){ const u16 hi = f2bf(bs[j]); pk.us[2*j] = hi; pk.us[2*j+1] = f2bf(bs[j] - bf2f(hi)); }
      *(short8*)&asp[row][il*16]     = pk.v2[0];
      *(short8*)&asp[row][il*16 + 8] = pk.v2[1];
    }
    __syncthreads();
    #pragma unroll 1
    for (int ks=0; ks<4; ++ks){
      const short8 a = *(const short8*)&asp[arow][ks*32 + q4*8];
      const int kg = 192 + c*128 + ks*32 + q4*8;
      #pragma unroll
      for (int nt=0; nt<NT; ++nt){
        const short8 bb = *(const short8*)&Bmat[(size_t)(nt*16+m16)*1472 + kg];
        acc[nt] = __builtin_amdgcn_mfma_f32_16x16x32_bf16(a, bb, acc[nt], 0, 0, 0);
      }
    }
  }

  #pragma unroll
  for (int nt=0; nt<NT; ++nt){
    const int col = nt*16 + m16;
    #pragma unroll
    for (int rg=0; rg<4; ++rg){
      const size_t row = r0 + w*16 + q4*4 + rg;
      const float v = acc[nt][rg];
      if constexpr (!FINAL){
        Yout[row*80 + col] = v;
      } else {
        if (col < 257){
          const float s = lodf(slope, col, isbf);
          const float o = 1.2f * sigm(s*v);
          if (isbf) ((u16*)Obuf)[row*257 + col] = f2bf(o);
          else      ((float*)Obuf)[row*257 + col] = o;
        }
      }
    }
  }
}

// ============================= launcher =============================
extern "C" void kernel_launch(void* const* d_in, const int* in_sizes, int n_in,
                              void* d_out, int out_size, void* d_ws, size_t ws_size,
                              hipStream_t stream)
{
  (void)in_sizes; (void)n_in; (void)out_size; (void)ws_size;
  const void* x     = d_in[0];
  // d_in[1] = lengths (unused)
  const void* f0Wih = d_in[2];  const void* f0Whh = d_in[3];
  const void* f0bih = d_in[4];  const void* f0bhh = d_in[5];
  const void* f1Wih = d_in[6];  const void* f1Whh = d_in[7];
  const void* f1bih = d_in[8];  const void* f1bhh = d_in[9];
  const void* b0Wih = d_in[10]; const void* b0Whh = d_in[11];
  const void* b0bih = d_in[12]; const void* b0bhh = d_in[13];
  const void* b1Wih = d_in[14]; const void* b1Whh = d_in[15];
  const void* b1bih = d_in[16]; const void* b1bhh = d_in[17];
  const void* k1b   = d_in[18]; const void* k1s   = d_in[19]; const void* k1sc = d_in[20];
  const void* k2b   = d_in[21]; const void* k2s   = d_in[22]; const void* k2sc = d_in[23];
  const void* slope = d_in[24];

  char* ws = (char*)d_ws;
  int*   flag  = (int*)(ws + OFF_FLAG);
  float* gi    = (float*)(ws + OFF_GI);
  float* hcat  = (float*)(ws + OFF_HCAT);
  float* k1out = (float*)(ws + OFF_KO);
  u16* B1a = (u16*)(ws + OFF_B1A);
  u16* B1b = (u16*)(ws + OFF_B1B);
  u16* B2  = (u16*)(ws + OFF_B2);
  u16* B3  = (u16*)(ws + OFF_B3);

  detect_kernel<<<1, 64, 0, stream>>>((const u16*)x, flag);
  prep_kernel<<<1300, 256, 0, stream>>>(f0Wih, b0Wih, k1b, k1s, k1sc, k2b, k2s, k2sc, flag, B1a, B1b, B2, B3);
  g1_kernel<<<1200, 256, 0, stream>>>(x, B1a, B1b, f0bih, b0bih, flag, gi);
  gru_kernel<<<128, 256, 0, stream>>>(gi,
      f0Whh, f0bhh, f1Wih, f1Whh, f1bih, f1bhh,
      b0Whh, b0bhh, b1Wih, b1Whh, b1bih, b1bhh, flag, hcat);
  kan_kernel<5,  false><<<600, 256, 0, stream>>>(hcat, B2, k1out, nullptr, nullptr, flag);
  kan_kernel<17, true ><<<600, 256, 0, stream>>>(k1out, B3, nullptr, d_out, slope, flag);
}

// Round 4
// 955.520 us; speedup vs baseline: 1.4209x; 1.3974x over previous
//
#include <hip/hip_runtime.h>
#include <cstdint>
#include <cstddef>

typedef unsigned short u16;
typedef unsigned int u32;
typedef __attribute__((ext_vector_type(8))) short short8;
typedef __attribute__((ext_vector_type(4))) float floatx4;

#define NROWS 38400   // B*T = 64*600

// ---- workspace layout (bytes) ----
#define OFF_FLAG 0u
#define OFF_GI   64u           // [2][38400][120] f32 = 36,864,000
#define OFF_HCAT 36864064u     // [38400][80] f32    = 12,288,000
#define OFF_B1A  49152064u     // [256][576] bf16    =    294,912
#define OFF_B1B  49446976u     // [256][576] bf16    =    294,912
#define OFF_B2   49741888u     // [80][1472] bf16    =    235,520
#define OFF_B3   49977408u     // [272][1472] bf16   =    800,768  (end ~50.78 MB)
#define OFF_KO   OFF_GI        // kan1out [38400][80] f32 overlays dead GI

__device__ inline float bf2f(u16 u){ union{u32 i; float f;} v; v.i = ((u32)u)<<16; return v.f; }
__device__ inline u16 f2bf(float f){
  u32 u = __float_as_uint(f);
  return (u16)((u + 0x7FFFu + ((u>>16)&1u)) >> 16);   // RNE
}
__device__ inline float lodf(const void* p, size_t i, int isbf){
  return isbf ? bf2f(((const u16*)p)[i]) : ((const float*)p)[i];
}
__device__ inline float rcpf(float x){ return __builtin_amdgcn_rcpf(x); }
__device__ inline float sigm(float x){ return rcpf(1.0f+__expf(-x)); }
__device__ inline float tanh_(float x){
  float e = __expf(-2.0f*fabsf(x)); float t = (1.0f-e)*rcpf(1.0f+e); return x<0.f ? -t : t;
}
__device__ inline float rdl(float v, int k){ return __int_as_float(__builtin_amdgcn_readlane(__float_as_int(v), k)); }

// ============================= detect input dtype (bf16 vs f32) =============================
__global__ void detect_kernel(const u16* __restrict__ xx, int* __restrict__ flag){
  const int l = threadIdx.x;
  const u16 w = xx[2*l];
  const int e = (w>>7)&0xFF;
  const unsigned long long m = __ballot(e >= 100 && e <= 133);
  if (l == 0) *flag = (__popcll(m) >= 32) ? 1 : 0;   // 1 = bf16
}

// ============================= prep: build padded bf16 B^T matrices =============================
__global__ void prep_kernel(const void* __restrict__ f0Wih, const void* __restrict__ b0Wih,
                            const void* __restrict__ k1b, const void* __restrict__ k1s, const void* __restrict__ k1sc,
                            const void* __restrict__ k2b, const void* __restrict__ k2s, const void* __restrict__ k2sc,
                            const int* __restrict__ flag,
                            u16* __restrict__ B1a, u16* __restrict__ B1b,
                            u16* __restrict__ B2, u16* __restrict__ B3)
{
  const int isbf = *flag;
  const int idx = blockIdx.x*256 + threadIdx.x;
  if (idx < 73728){
    const int j = idx/288, k = idx - j*288;
    float w = 0.f;
    if (k < 257 && j < 240)
      w = (j < 120) ? lodf(f0Wih, (size_t)j*257+k, isbf) : lodf(b0Wih, (size_t)(j-120)*257+k, isbf);
    const u16 hi = f2bf(w); const u16 lo = f2bf(w - bf2f(hi));
    B1a[(size_t)j*576 + 2*k] = hi; B1a[(size_t)j*576 + 2*k+1] = hi;
    B1b[(size_t)j*576 + 2*k] = lo; B1b[(size_t)j*576 + 2*k+1] = 0;
  } else if (idx < 132608){
    const int t = idx - 73728; const int n = t/736, m = t - n*736;
    float v = 0.f;
    if (m < 80) v = lodf(k1b, (size_t)n*80+m, isbf);
    else if (m >= 96){ const int m2 = m-96, i = m2>>3, g = m2&7;
      v = lodf(k1s, ((size_t)n*80+i)*8+g, isbf) * lodf(k1sc, (size_t)n*80+i, isbf); }
    const u16 vv = f2bf(v);
    B2[(size_t)n*1472 + 2*m] = vv; B2[(size_t)n*1472 + 2*m+1] = vv;
  } else {
    const int t = idx - 132608; const int n = t/736, m = t - n*736;
    float v = 0.f;
    if (n < 257){
      if (m < 80) v = lodf(k2b, (size_t)n*80+m, isbf);
      else if (m >= 96){ const int m2 = m-96, i = m2>>3, g = m2&7;
        v = lodf(k2s, ((size_t)n*80+i)*8+g, isbf) * lodf(k2sc, (size_t)n*80+i, isbf); }
    }
    const u16 vv = f2bf(v);
    B3[(size_t)n*1472 + 2*m] = vv; B3[(size_t)n*1472 + 2*m+1] = vv;
  }
}

// ============================= G1: gi = x @ Wih^T + bih, MFMA, nt-split across waves =============================
__launch_bounds__(256)
__global__ void g1_kernel(const void* __restrict__ x, const u16* __restrict__ B1a, const u16* __restrict__ B1b,
                          const void* __restrict__ f0bih, const void* __restrict__ b0bih,
                          const int* __restrict__ flag, float* __restrict__ gi)
{
  __shared__ __attribute__((aligned(16))) u16 As[32][576];
  const int isbf = *flag;
  const int tid = threadIdx.x;
  const size_t r0 = (size_t)blockIdx.x * 32;
  {
    const int row = tid>>3, kk = tid&7;
    #pragma unroll
    for (int it=0; it<36; ++it){
      const int k = kk + it*8;
      const float v = (k < 257) ? lodf(x, (r0+row)*257 + k, isbf) : 0.f;
      const u16 hi = f2bf(v);
      As[row][2*k] = hi; As[row][2*k+1] = f2bf(v - bf2f(hi));
    }
  }
  __syncthreads();
  const int w = tid>>6, l = tid&63, m16 = l&15, q4 = l>>4;
  // NT=15 split {4,4,4,3}
  const int cnt = (w<3)?4:3;
  const int ntlo = w*4;
  floatx4 acc[4][2];
  #pragma unroll
  for (int j=0;j<4;++j) for (int s=0;s<2;++s){ floatx4 z={0.f,0.f,0.f,0.f}; acc[j][s]=z; }
  #pragma unroll 1
  for (int ks=0; ks<18; ++ks){
    const short8 a0 = *(const short8*)&As[m16][ks*32 + q4*8];
    const short8 a1 = *(const short8*)&As[16+m16][ks*32 + q4*8];
    #pragma unroll
    for (int j=0;j<4;++j){
      if (j < cnt){
        const int nt = ntlo + j;
        const short8 ba = *(const short8*)&B1a[(size_t)(nt*16+m16)*576 + ks*32 + q4*8];
        acc[j][0] = __builtin_amdgcn_mfma_f32_16x16x32_bf16(a0, ba, acc[j][0], 0, 0, 0);
        acc[j][1] = __builtin_amdgcn_mfma_f32_16x16x32_bf16(a1, ba, acc[j][1], 0, 0, 0);
        if (!isbf){
          const short8 bb = *(const short8*)&B1b[(size_t)(nt*16+m16)*576 + ks*32 + q4*8];
          acc[j][0] = __builtin_amdgcn_mfma_f32_16x16x32_bf16(a0, bb, acc[j][0], 0, 0, 0);
          acc[j][1] = __builtin_amdgcn_mfma_f32_16x16x32_bf16(a1, bb, acc[j][1], 0, 0, 0);
        }
      }
    }
  }
  #pragma unroll
  for (int j=0;j<4;++j){
    if (j < cnt){
      const int col = (ntlo+j)*16 + m16;
      if (col < 240){
        const int dsel = (col < 120) ? 0 : 1;
        const int jj = (col < 120) ? col : col-120;
        const float bias = (col < 120) ? lodf(f0bih, col, isbf) : lodf(b0bih, col-120, isbf);
        #pragma unroll
        for (int s=0;s<2;++s){
          #pragma unroll
          for (int rg=0; rg<4; ++rg){
            const size_t row = r0 + s*16 + q4*4 + rg;
            gi[((size_t)dsel*NROWS + row)*120 + jj] = acc[j][s][rg] + bias;
          }
        }
      }
    }
  }
}

// ============================= GRU =============================
// 32-tick gi chunks staged by wave3; 2 ticks per barrier; hcat buffered in LDS, flushed per 64-tick window.
__device__ inline void stage_chunk32(const char* __restrict__ gid, int4* dst, int c, int d, int bat, int l)
{
  const long long rbase = (long long)bat*600 + (d ? (568 - 32*c) : (32*c));
  const long long base = rbase * 480;
  const long long lim = (long long)NROWS * 480;
  int4 v[15];
  #pragma unroll
  for (int j=0; j<15; ++j){
    const long long off = base + (long long)(j*64 + l)*16;
    int4 z; z.x=0; z.y=0; z.z=0; z.w=0;
    v[j] = (off >= 0 && off+16 <= lim) ? *(const int4*)(gid + off) : z;
  }
  #pragma unroll
  for (int j=0; j<15; ++j) dst[j*64 + l] = v[j];
}

__launch_bounds__(256, 1)
__global__ void gru_kernel(const float* __restrict__ gi,
  const void* __restrict__ f0Whh, const void* __restrict__ f0bhh,
  const void* __restrict__ f1Wih, const void* __restrict__ f1Whh, const void* __restrict__ f1bih, const void* __restrict__ f1bhh,
  const void* __restrict__ b0Whh, const void* __restrict__ b0bhh,
  const void* __restrict__ b1Wih, const void* __restrict__ b1Whh, const void* __restrict__ b1bih, const void* __restrict__ b1bhh,
  const int* __restrict__ flag, float* __restrict__ hcat)
{
  __shared__ int4 chunkbuf[2][960];          // 2 x 32 ticks x 120 f32 = 30720 B
  __shared__ float hbuf[2][64][40];          // hcat window buffer, 20480 B
  __shared__ float h0buf[2][2][40];
  __shared__ float gi1buf[2][2][3][40];
  const int isbf = *flag;
  const int tid = threadIdx.x, w = tid>>6, l = tid&63;
  const int blk = blockIdx.x, d = blk>>6, bat = blk&63;
  const int li = (l < 40) ? l : 39;
  const char* gid = (const char*)(gi + (size_t)d*NROWS*120);

  const void *Wsrc = 0, *bsrc = 0;
  if (w == 0){ Wsrc = d ? b0Whh : f0Whh; bsrc = d ? b0bhh : f0bhh; }
  else if (w == 1){ Wsrc = d ? b1Wih : f1Wih; bsrc = d ? b1bih : f1bih; }
  else if (w == 2){ Wsrc = d ? b1Whh : f1Whh; bsrc = d ? b1bhh : f1bhh; }

  float WA[40], WB[40], WC[40];
  float bA = 0.f, bB = 0.f, bC = 0.f;
  if (w < 3){
    #pragma unroll
    for (int k=0; k<40; ++k){
      WA[k] = lodf(Wsrc, (size_t)(     li)*40 + k, isbf);
      WB[k] = lodf(Wsrc, (size_t)(40 + li)*40 + k, isbf);
      WC[k] = lodf(Wsrc, (size_t)(80 + li)*40 + k, isbf);
    }
    bA = lodf(bsrc, li, isbf); bB = lodf(bsrc, 40+li, isbf); bC = lodf(bsrc, 80+li, isbf);
    // pin weights into VGPRs: forbid load-rematerialization by the register allocator
    #pragma unroll
    for (int k=0; k<40; ++k){
      asm volatile("" : "+v"(WA[k]), "+v"(WB[k]), "+v"(WC[k]));
    }
  } else {
    stage_chunk32(gid, &chunkbuf[0][0], 0, d, bat, l);
  }
  float hs = 0.f;

  auto cell = [&](float hsv, float gA, float gB, float gC) -> float {
    float ar = bA, az = bB, an = bC;
    #pragma unroll
    for (int k=0; k<40; ++k){ const float hk = rdl(hsv, k); ar += WA[k]*hk; az += WB[k]*hk; an += WC[k]*hk; }
    const float r = sigm(gA + ar), z = sigm(gB + az);
    const float n = tanh_(gC + r*an);
    return (1.f - z)*n + z*hsv;
  };
  auto mv3 = [&](float hsv, float& oa, float& ob, float& oc){
    float ar = bA, az = bB, an = bC;
    #pragma unroll
    for (int k=0; k<40; ++k){ const float hk = rdl(hsv, k); ar += WA[k]*hk; az += WB[k]*hk; an += WC[k]*hk; }
    oa = ar; ob = az; oc = an;
  };

  __syncthreads();

  #pragma unroll 1
  for (int i=0; i<302; ++i){
    if (w == 0){
      if (i < 300){ // layer0, ticks 2i, 2i+1
        const int cc = (i>>4)&1;
        const int ta = (2*i)&31;
        const float* base = (const float*)&chunkbuf[cc][0];
        const float* ra = base + (d ? (31-ta)   : ta  )*120;
        const float* rb = base + (d ? (31-ta-1) : ta+1)*120;
        const float gAa=ra[li], gBa=ra[40+li], gCa=ra[80+li];
        const float gAb=rb[li], gBb=rb[40+li], gCb=rb[80+li];
        hs = cell(hs, gAa, gBa, gCa);
        if (l < 40) h0buf[i&1][0][l] = hs;
        hs = cell(hs, gAb, gBb, gCb);
        if (l < 40) h0buf[i&1][1][l] = hs;
      }
    } else if (w == 1){
      if (i >= 1 && i <= 300){ // layer1 input-side for wave0's pair from i-1
        const int p = (i-1)&1;
        const float ha = h0buf[p][0][li];
        const float hb = h0buf[p][1][li];
        float a0,a1,a2, b0,b1,b2;
        mv3(ha, a0, a1, a2);
        mv3(hb, b0, b1, b2);
        if (l < 40){
          gi1buf[i&1][0][0][l]=a0; gi1buf[i&1][0][1][l]=a1; gi1buf[i&1][0][2][l]=a2;
          gi1buf[i&1][1][0][l]=b0; gi1buf[i&1][1][1][l]=b1; gi1buf[i&1][1][2][l]=b2;
        }
      }
    } else if (w == 2){
      if (i >= 2){ // layer1 cell for ticks 2(i-2), 2(i-2)+1
        const int p = (i-1)&1;
        const float gAa=gi1buf[p][0][0][li], gBa=gi1buf[p][0][1][li], gCa=gi1buf[p][0][2][li];
        const float gAb=gi1buf[p][1][0][li], gBb=gi1buf[p][1][1][li], gCb=gi1buf[p][1][2][li];
        const int ta2 = 2*(i-2);
        const int wp = (ta2>>6)&1, sa = ta2&63;
        hs = cell(hs, gAa, gBa, gCa);
        if (l < 40) hbuf[wp][sa][l] = hs;
        hs = cell(hs, gAb, gBb, gCb);
        if (l < 40) hbuf[wp][sa+1][l] = hs;
      }
    } else {
      if ((i & 15) == 0){ const int c1 = (i>>4) + 1; if (c1 <= 18) stage_chunk32(gid, &chunkbuf[c1&1][0], c1, d, bat, l); }
      if ((i & 31) == 2){ // flush hcat window m-1 (64 ticks)
        const int m = i>>5;
        if (m >= 1){
          const int t0 = 64*(m-1);
          const int4* src = (const int4*)&hbuf[(m-1)&1][0][0];
          #pragma unroll
          for (int q=0; q<10; ++q){
            const int f = q*64 + l;
            const int t = f/10, j4 = f - 10*t;
            int4 v = src[t*10 + j4];
            *(int4*)&hcat[((size_t)bat*600 + t0 + t)*80 + d*40 + j4*4] = v;
          }
        }
      }
    }
    __syncthreads();
  }
  // flush final window (ticks 576..599, parity (9&1)=1)
  if (tid < 240){
    const int t = tid/10, j4 = tid - 10*t;
    const int4* src = (const int4*)&hbuf[1][0][0];
    int4 v = src[t*10 + j4];
    *(int4*)&hcat[((size_t)bat*600 + 576 + t)*80 + d*40 + j4*4] = v;
  }
}

// ============================= KAN: fused A-construction + MFMA, nt-split across waves =============================
__device__ inline void spline8(float x, float* bs)
{
  float g[12];
  #pragma unroll
  for (int j=0; j<12; ++j) g[j] = (float)(j-3)*0.4f - 1.0f;
  float b0[11];
  #pragma unroll
  for (int j=0; j<11; ++j) b0[j] = (x >= g[j] && x < g[j+1]) ? 1.f : 0.f;
  float b1[10];
  #pragma unroll
  for (int j=0; j<10; ++j)
    b1[j] = (x - g[j])*(1.0f/(g[j+1]-g[j]))*b0[j] + (g[j+2] - x)*(1.0f/(g[j+2]-g[j+1]))*b0[j+1];
  float b2[9];
  #pragma unroll
  for (int j=0; j<9; ++j)
    b2[j] = (x - g[j])*(1.0f/(g[j+2]-g[j]))*b1[j] + (g[j+3] - x)*(1.0f/(g[j+3]-g[j+1]))*b1[j+1];
  #pragma unroll
  for (int j=0; j<8; ++j)
    bs[j] = (x - g[j])*(1.0f/(g[j+3]-g[j]))*b2[j] + (g[j+4] - x)*(1.0f/(g[j+4]-g[j+1]))*b2[j+1];
}

template<int NT, bool FINAL>
__launch_bounds__(256)
__global__ void kan_kernel(const float* __restrict__ Xin, const u16* __restrict__ Bmat,
                           float* __restrict__ Yout, void* __restrict__ Obuf,
                           const void* __restrict__ slope, const int* __restrict__ flag)
{
  constexpr int MAXC = (NT+3)/4;
  __shared__ __attribute__((aligned(16))) float xs[64][80];
  __shared__ __attribute__((aligned(16))) u16 abase[64][192];
  __shared__ __attribute__((aligned(16))) u16 asp[64][128];
  const int isbf = *flag;
  const int tid = threadIdx.x;
  const size_t r0 = (size_t)blockIdx.x * 64;

  for (int idx=tid; idx<5120; idx+=256) ((float*)xs)[idx] = Xin[r0*80 + idx];
  __syncthreads();
  for (int idx=tid; idx<6144; idx+=256){
    const int row = idx/96, m = idx - row*96;
    float v = 0.f;
    if (m < 80){ const float xv = xs[row][m]; v = xv * sigm(xv); }
    const u16 hi = f2bf(v);
    abase[row][2*m] = hi; abase[row][2*m+1] = f2bf(v - bf2f(hi));
  }
  __syncthreads();

  const int w = tid>>6, l = tid&63, m16 = l&15, q4 = l>>4;
  const int cbase = NT>>2, rem = NT&3;
  const int cnt  = cbase + ((w < rem) ? 1 : 0);
  const int ntlo = w*cbase + ((w < rem) ? w : rem);
  floatx4 acc[MAXC][4];
  #pragma unroll
  for (int j=0;j<MAXC;++j) for (int s=0;s<4;++s){ floatx4 z={0.f,0.f,0.f,0.f}; acc[j][s]=z; }

  #pragma unroll 1
  for (int ks=0; ks<6; ++ks){
    short8 a[4];
    #pragma unroll
    for (int s=0;s<4;++s) a[s] = *(const short8*)&abase[s*16+m16][ks*32 + q4*8];
    #pragma unroll
    for (int j=0;j<MAXC;++j){
      if (j < cnt){
        const short8 b = *(const short8*)&Bmat[(size_t)((ntlo+j)*16+m16)*1472 + ks*32 + q4*8];
        #pragma unroll
        for (int s=0;s<4;++s) acc[j][s] = __builtin_amdgcn_mfma_f32_16x16x32_bf16(a[s], b, acc[j][s], 0, 0, 0);
      }
    }
  }
  #pragma unroll 1
  for (int c=0; c<10; ++c){
    __syncthreads();
    for (int idx=tid; idx<512; idx+=256){
      const int row = idx>>3, il = idx&7;
      const float xv = xs[row][c*8 + il];
      float bs[8]; spline8(xv, bs);
      union { u16 us[16]; short8 v2[2]; } pk;
      #pragma unroll
      for (int j=0; j<8; ++j){ const u16 hi = f2bf(bs[j]); pk.us[2*j] = hi; pk.us[2*j+1] = f2bf(bs[j] - bf2f(hi)); }
      *(short8*)&asp[row][il*16]     = pk.v2[0];
      *(short8*)&asp[row][il*16 + 8] = pk.v2[1];
    }
    __syncthreads();
    #pragma unroll 1
    for (int ks=0; ks<4; ++ks){
      short8 a[4];
      #pragma unroll
      for (int s=0;s<4;++s) a[s] = *(const short8*)&asp[s*16+m16][ks*32 + q4*8];
      const int kg = 192 + c*128 + ks*32 + q4*8;
      #pragma unroll
      for (int j=0;j<MAXC;++j){
        if (j < cnt){
          const short8 b = *(const short8*)&Bmat[(size_t)((ntlo+j)*16+m16)*1472 + kg];
          #pragma unroll
          for (int s=0;s<4;++s) acc[j][s] = __builtin_amdgcn_mfma_f32_16x16x32_bf16(a[s], b, acc[j][s], 0, 0, 0);
        }
      }
    }
  }

  #pragma unroll
  for (int j=0;j<MAXC;++j){
    if (j < cnt){
      const int col = (ntlo+j)*16 + m16;
      #pragma unroll
      for (int s=0;s<4;++s){
        #pragma unroll
        for (int rg=0; rg<4; ++rg){
          const size_t row = r0 + s*16 + q4*4 + rg;
          const float v = acc[j][s][rg];
          if constexpr (!FINAL){
            Yout[row*80 + col] = v;
          } else {
            if (col < 257){
              const float sl = lodf(slope, col, isbf);
              const float o = 1.2f * sigm(sl*v);
              if (isbf) ((u16*)Obuf)[row*257 + col] = f2bf(o);
              else      ((float*)Obuf)[row*257 + col] = o;
            }
          }
        }
      }
    }
  }
}

// ============================= launcher =============================
extern "C" void kernel_launch(void* const* d_in, const int* in_sizes, int n_in,
                              void* d_out, int out_size, void* d_ws, size_t ws_size,
                              hipStream_t stream)
{
  (void)in_sizes; (void)n_in; (void)out_size; (void)ws_size;
  const void* x     = d_in[0];
  const void* f0Wih = d_in[2];  const void* f0Whh = d_in[3];
  const void* f0bih = d_in[4];  const void* f0bhh = d_in[5];
  const void* f1Wih = d_in[6];  const void* f1Whh = d_in[7];
  const void* f1bih = d_in[8];  const void* f1bhh = d_in[9];
  const void* b0Wih = d_in[10]; const void* b0Whh = d_in[11];
  const void* b0bih = d_in[12]; const void* b0bhh = d_in[13];
  const void* b1Wih = d_in[14]; const void* b1Whh = d_in[15];
  const void* b1bih = d_in[16]; const void* b1bhh = d_in[17];
  const void* k1b   = d_in[18]; const void* k1s   = d_in[19]; const void* k1sc = d_in[20];
  const void* k2b   = d_in[21]; const void* k2s   = d_in[22]; const void* k2sc = d_in[23];
  const void* slope = d_in[24];

  char* ws = (char*)d_ws;
  int*   flag  = (int*)(ws + OFF_FLAG);
  float* gi    = (float*)(ws + OFF_GI);
  float* hcat  = (float*)(ws + OFF_HCAT);
  float* k1out = (float*)(ws + OFF_KO);
  u16* B1a = (u16*)(ws + OFF_B1A);
  u16* B1b = (u16*)(ws + OFF_B1B);
  u16* B2  = (u16*)(ws + OFF_B2);
  u16* B3  = (u16*)(ws + OFF_B3);

  detect_kernel<<<1, 64, 0, stream>>>((const u16*)x, flag);
  prep_kernel<<<1300, 256, 0, stream>>>(f0Wih, b0Wih, k1b, k1s, k1sc, k2b, k2s, k2sc, flag, B1a, B1b, B2, B3);
  g1_kernel<<<1200, 256, 0, stream>>>(x, B1a, B1b, f0bih, b0bih, flag, gi);
  gru_kernel<<<128, 256, 0, stream>>>(gi,
      f0Whh, f0bhh, f1Wih, f1Whh, f1bih, f1bhh,
      b0Whh, b0bhh, b1Wih, b1Whh, b1bih, b1bhh, flag, hcat);
  kan_kernel<5,  false><<<600, 256, 0, stream>>>(hcat, B2, k1out, nullptr, nullptr, flag);
  kan_kernel<17, true ><<<600, 256, 0, stream>>>(k1out, B3, nullptr, d_out, slope, flag);
}